// Round 2
// baseline (323.282 us; speedup 1.0000x reference)
//
#include <hip/hip_runtime.h>
#include <hip/hip_bf16.h>
#include <math.h>

// ---- problem constants ----
#define NROWS 8192
#define DDIM  64
#define HBINS 4096      // pdist histogram bins, width 0.125 over [0, 512)
#define RMIX  0.1f

typedef __attribute__((ext_vector_type(4))) float  f4;
typedef __attribute__((ext_vector_type(8))) short  bf16x8;  // 8 bf16 = 4 VGPRs (MFMA A/B frag)
typedef __attribute__((ext_vector_type(4))) unsigned short us4;

__device__ __forceinline__ unsigned short f2bf(float f) {
  // round-to-nearest-even f32 -> bf16 (inputs are finite normals; no NaN handling)
  unsigned u = __builtin_bit_cast(unsigned, f);
  u += 0x7fffu + ((u >> 16) & 1u);
  return (unsigned short)(u >> 16);
}

// ---- K0: zero the global histogram (ws is poisoned 0xAA each call) ----
__global__ void zero_hist_k(unsigned* __restrict__ hist) {
  hist[blockIdx.x * 256 + threadIdx.x] = 0u;
}

// ---- K1: exact f32 row norms |x_i|^2, |y_j|^2 ----
__global__ void norms_k(const float* __restrict__ x, const float* __restrict__ y,
                        float* __restrict__ sx, float* __restrict__ sy) {
  int i = blockIdx.x * 256 + threadIdx.x;          // 0 .. 2*NROWS-1
  const float* src = (i < NROWS) ? (x + (size_t)i * DDIM)
                                 : (y + (size_t)(i - NROWS) * DDIM);
  float s = 0.f;
#pragma unroll
  for (int d = 0; d < DDIM / 4; ++d) {
    f4 v = *(const f4*)(src + d * 4);
    s += v.x * v.x + v.y * v.y + v.z * v.z + v.w * v.w;
  }
  if (i < NROWS) sx[i] = s; else sy[i - NROWS] = s;
}

// ---- K2: histogram of pdist over a 512x512 (stride-16) subsample ----
__global__ void hist_k(const float* __restrict__ x, const float* __restrict__ y,
                       const float* __restrict__ sx, const float* __restrict__ sy,
                       unsigned* __restrict__ hist) {
  __shared__ unsigned lh[HBINS];
  for (int i = threadIdx.x; i < HBINS; i += 256) lh[i] = 0u;
  __syncthreads();
  int base = blockIdx.x * 1024;                    // 256 blocks * 1024 = 512*512 pairs
#pragma unroll
  for (int k = 0; k < 4; ++k) {
    int p = base + k * 256 + threadIdx.x;
    int i = (p >> 9) << 4;                         // sampled x row (stride 16)
    int j = (p & 511) << 4;                        // sampled y row (stride 16)
    const f4* xr = (const f4*)(x + (size_t)i * DDIM);
    const f4* yr = (const f4*)(y + (size_t)j * DDIM);
    float inner = 0.f;
#pragma unroll
    for (int d = 0; d < DDIM / 4; ++d) {
      f4 a = xr[d], b = yr[d];
      inner += a.x * b.x + a.y * b.y + a.z * b.z + a.w * b.w;
    }
    float pd = sx[i] + sy[j] - 2.f * inner;
    int bin = (int)(pd * 8.f);
    bin = bin < 0 ? 0 : (bin > HBINS - 1 ? HBINS - 1 : bin);
    atomicAdd(&lh[bin], 1u);
  }
  __syncthreads();
  for (int i = threadIdx.x; i < HBINS; i += 256) {
    unsigned v = lh[i];
    if (v) atomicAdd(&hist[i], v);
  }
}

// ---- K3: parallel median-from-histogram -> c1 = 1/(2*sigma) = ln(N+1)/median ----
__global__ void scan_k(const unsigned* __restrict__ hist, float* __restrict__ c1) {
  __shared__ unsigned ps[256];
  int t = threadIdx.x;
  unsigned v[16]; unsigned ls = 0;
#pragma unroll
  for (int i = 0; i < 16; ++i) { v[i] = hist[t * 16 + i]; ls += v[i]; }
  ps[t] = ls;
  __syncthreads();
  unsigned total = 0;
  for (int i = 0; i < 256; ++i) total += ps[i];    // all threads, pipelined LDS reads
  unsigned half = (total + 1) / 2;
  unsigned before = 0;
  for (int i = 0; i < t; ++i) before += ps[i];
  if (before < half && before + ls >= half) {      // exactly one thread
    unsigned cum = before; int mb = t * 16 + 15;
#pragma unroll
    for (int i = 0; i < 16; ++i) { cum += v[i]; if (cum >= half) { mb = t * 16 + i; break; } }
    float median = ((float)mb + 0.5f) * 0.125f;
    c1[0] = logf((float)(NROWS + 1)) / median;     // 1/(2*sigma)
  }
}

// ---- K4: main fused kernel: 128x128 tile, bf16 MFMA 16x16x32, fused epilogue ----
__global__ __launch_bounds__(256) void kxy_k(
    const float* __restrict__ x, const float* __restrict__ y,
    const float* __restrict__ sx, const float* __restrict__ sy,
    const float* __restrict__ c1p, float* __restrict__ out) {
  // XOR-swizzled LDS tiles: [128 rows][64 bf16] -> 128B row stride.
  // Unswizzled, frag reads (16 lanes, stride 128B) would be a 16-way bank
  // conflict; byte ^= (row&7)<<4 spreads rows 0..7 over 8 16B slots (2-way = free).
  __shared__ unsigned short lA[128 * 64];
  __shared__ unsigned short lB[128 * 64];

  // XCD-bijective block swizzle (nwg=4096, 4096%8==0)
  int wg  = blockIdx.x;
  int swz = (wg & 7) * 512 + (wg >> 3);
  int bm  = swz >> 6, bn = swz & 63;

  const int tid = threadIdx.x;
  const float* xT = x + (size_t)bm * 128 * DDIM;
  const float* yT = y + (size_t)bn * 128 * DDIM;

  // stage + convert: 128x64 f32 -> bf16, both tiles
#pragma unroll
  for (int it = 0; it < 8; ++it) {
    int f   = tid + it * 256;        // float4 index, 0..2047
    int row = f >> 4;                // 0..127
    int c4  = (f & 15) << 2;         // 0..60
    f4 a = *(const f4*)(xT + row * DDIM + c4);
    f4 b = *(const f4*)(yT + row * DDIM + c4);
    us4 pa, pb;
    pa.x = f2bf(a.x); pa.y = f2bf(a.y); pa.z = f2bf(a.z); pa.w = f2bf(a.w);
    pb.x = f2bf(b.x); pb.y = f2bf(b.y); pb.z = f2bf(b.z); pb.w = f2bf(b.w);
    int off = row * 128 + (c4 << 1);           // byte offset, 8B aligned
    int sz  = off ^ ((row & 7) << 4);
    *(us4*)((char*)lA + sz) = pa;
    *(us4*)((char*)lB + sz) = pb;
  }
  __syncthreads();

  const int lane = tid & 63;
  const int wv   = tid >> 6;
  const int wr   = wv >> 1, wc = wv & 1;       // 2x2 waves, 64x64 each
  const int lr   = lane & 15;                  // frag row (A) / col (B)
  const int kg   = lane >> 4;                  // k-octet 0..3

  f4 acc[4][4];
  f4 zero = {0.f, 0.f, 0.f, 0.f};
#pragma unroll
  for (int m = 0; m < 4; ++m)
#pragma unroll
    for (int n = 0; n < 4; ++n) acc[m][n] = zero;

#pragma unroll
  for (int ks = 0; ks < 2; ++ks) {             // K = 64 = 2 x 32
    bf16x8 af[4], bf[4];
    int kB = (ks * 32 + kg * 8) << 1;          // byte offset of k-octet, 16B aligned
#pragma unroll
    for (int m = 0; m < 4; ++m) {
      int r = wr * 64 + m * 16 + lr;
      int off = r * 128 + kB;
      af[m] = *(const bf16x8*)((const char*)lA + (off ^ ((r & 7) << 4)));
    }
#pragma unroll
    for (int n = 0; n < 4; ++n) {
      int r = wc * 64 + n * 16 + lr;
      int off = r * 128 + kB;
      bf[n] = *(const bf16x8*)((const char*)lB + (off ^ ((r & 7) << 4)));
    }
#pragma unroll
    for (int m = 0; m < 4; ++m)
#pragma unroll
      for (int n = 0; n < 4; ++n)
        acc[m][n] = __builtin_amdgcn_mfma_f32_16x16x32_bf16(af[m], bf[n], acc[m][n], 0, 0, 0);
  }

  // fused epilogue: pdist -> exp + poly
  float c1 = c1p[0];                           // 1/(2*sigma)
  int rowBase = bm * 128 + wr * 64 + kg * 4;   // C/D: row=(lane>>4)*4+reg, col=lane&15
  float sxv[4][4];
#pragma unroll
  for (int m = 0; m < 4; ++m)
#pragma unroll
    for (int rg = 0; rg < 4; ++rg)
      sxv[m][rg] = sx[rowBase + m * 16 + rg];

  int colBase = bn * 128 + wc * 64 + lr;
#pragma unroll
  for (int n = 0; n < 4; ++n) {
    int col = colBase + n * 16;
    float syv = sy[col];
#pragma unroll
    for (int m = 0; m < 4; ++m) {
#pragma unroll
      for (int rg = 0; rg < 4; ++rg) {
        float inner = acc[m][n][rg];
        float pd = sxv[m][rg] + syv - 2.f * inner;
        int row = rowBase + m * 16 + rg;
        out[(size_t)row * NROWS + col] = __expf(-pd * c1) + RMIX * inner * inner;
      }
    }
  }
}

extern "C" void kernel_launch(void* const* d_in, const int* in_sizes, int n_in,
                              void* d_out, int out_size, void* d_ws, size_t ws_size,
                              hipStream_t stream) {
  const float* x = (const float*)d_in[0];
  const float* y = (const float*)d_in[1];
  float* out = (float*)d_out;

  // workspace layout: sx[8192] f32 | sy[8192] f32 | hist[4096] u32 | c1[1] f32
  float*    sx   = (float*)d_ws;
  float*    sy   = sx + NROWS;
  unsigned* hist = (unsigned*)(sy + NROWS);
  float*    c1   = (float*)(hist + HBINS);

  hipLaunchKernelGGL(zero_hist_k, dim3(HBINS / 256), dim3(256), 0, stream, hist);
  hipLaunchKernelGGL(norms_k, dim3(2 * NROWS / 256), dim3(256), 0, stream, x, y, sx, sy);
  hipLaunchKernelGGL(hist_k, dim3(256), dim3(256), 0, stream, x, y, sx, sy, hist);
  hipLaunchKernelGGL(scan_k, dim3(1), dim3(256), 0, stream, hist, c1);
  hipLaunchKernelGGL(kxy_k, dim3(4096), dim3(256), 0, stream, x, y, sx, sy, c1, out);
}

// Round 3
// 321.557 us; speedup vs baseline: 1.0054x; 1.0054x over previous
//
#include <hip/hip_runtime.h>
#include <hip/hip_bf16.h>
#include <math.h>

// ---- problem constants ----
#define NROWS 8192
#define DDIM  64
#define HBINS 4096      // pdist histogram bins, width 0.125 over [0, 512)
#define RMIX  0.1f

typedef __attribute__((ext_vector_type(4))) float  f4;
typedef __attribute__((ext_vector_type(8))) short  bf16x8;  // 8 bf16 = 4 VGPRs (MFMA A/B frag)
typedef __attribute__((ext_vector_type(4))) unsigned short us4;

__device__ __forceinline__ unsigned short f2bf(float f) {
  // round-to-nearest-even f32 -> bf16 (inputs are finite normals)
  unsigned u = __builtin_bit_cast(unsigned, f);
  u += 0x7fffu + ((u >> 16) & 1u);
  return (unsigned short)(u >> 16);
}

// ---- K1: exact f32 row norms (coalesced, shuffle-reduced) + hist zeroing ----
// grid 65 x 256. Blocks 0..63: 256 rows each of concat(x,y). Block 64: zero hist.
__global__ __launch_bounds__(256) void norms_k(
    const float* __restrict__ x, const float* __restrict__ y,
    float* __restrict__ sx, float* __restrict__ sy, unsigned* __restrict__ hist) {
  int b = blockIdx.x, tid = threadIdx.x;
  if (b == 64) {
    for (int i = tid; i < HBINS; i += 256) hist[i] = 0u;
    return;
  }
  int lane = tid & 63, w = tid >> 6;
  int l15 = lane & 15, lg = lane >> 4;
#pragma unroll
  for (int it = 0; it < 16; ++it) {
    int grow = b * 256 + it * 16 + w * 4 + lg;     // 0..16383
    const float* src = (grow < NROWS) ? x + (size_t)grow * DDIM
                                      : y + (size_t)(grow - NROWS) * DDIM;
    f4 v = *(const f4*)(src + l15 * 4);            // 16 lanes cover one row; wave reads 1KB contiguous
    float s = v.x * v.x + v.y * v.y + v.z * v.z + v.w * v.w;
    s += __shfl_xor(s, 1);
    s += __shfl_xor(s, 2);
    s += __shfl_xor(s, 4);
    s += __shfl_xor(s, 8);                         // reduce within the 16-lane row group
    if (l15 == 0) { if (grow < NROWS) sx[grow] = s; else sy[grow - NROWS] = s; }
  }
}

// ---- K2: pdist histogram over 256x256 stride-32 subsample, LDS-staged ----
// grid 64 x 256. Block b: x-rows {(4b+w)*32}, all 256 sampled y-rows.
__global__ __launch_bounds__(256) void hist_k(
    const float* __restrict__ x, const float* __restrict__ y,
    const float* __restrict__ sx, const float* __restrict__ sy,
    unsigned* __restrict__ hist) {
  __shared__ float yl[256][68];                    // pad 64->68: f4 reads conflict-free, 16B-aligned rows
  __shared__ float xr[4][68];
  __shared__ unsigned lh[HBINS];
  int tid = threadIdx.x;
  for (int i = tid; i < HBINS; i += 256) lh[i] = 0u;
  for (int f = tid; f < 4096; f += 256) {          // stage 256 sampled y rows
    int r = f >> 4, c4 = (f & 15) << 2;
    *(f4*)&yl[r][c4] = *(const f4*)(y + (size_t)(r * 32) * DDIM + c4);
  }
  if (tid < 64) {                                  // stage this block's 4 x rows
    int r = tid >> 4, c4 = (tid & 15) << 2;
    int gx = (blockIdx.x * 4 + r) * 32;
    *(f4*)&xr[r][c4] = *(const f4*)(x + (size_t)gx * DDIM + c4);
  }
  __syncthreads();
  int w = tid >> 6, lane = tid & 63;
  float sxv = sx[(blockIdx.x * 4 + w) * 32];
#pragma unroll
  for (int jj = 0; jj < 4; ++jj) {
    int j = jj * 64 + lane;
    float inner = 0.f;
#pragma unroll
    for (int k4 = 0; k4 < 16; ++k4) {
      f4 a = *(const f4*)&xr[w][k4 * 4];           // broadcast (wave-uniform)
      f4 bv = *(const f4*)&yl[j][k4 * 4];          // conflict-free (stride 68)
      inner += a.x * bv.x + a.y * bv.y + a.z * bv.z + a.w * bv.w;
    }
    float pd = sxv + sy[j * 32] - 2.f * inner;
    int bin = (int)(pd * 8.f);
    bin = bin < 0 ? 0 : (bin > HBINS - 1 ? HBINS - 1 : bin);
    atomicAdd(&lh[bin], 1u);
  }
  __syncthreads();
  for (int i = tid; i < HBINS; i += 256) {
    unsigned v = lh[i];
    if (v) atomicAdd(&hist[i], v);
  }
}

// ---- K3: median-from-histogram -> c1 = 1/(2*sigma) = ln(N+1)/median ----
__global__ void scan_k(const unsigned* __restrict__ hist, float* __restrict__ c1) {
  __shared__ unsigned ps[256];
  int t = threadIdx.x;
  unsigned v[16]; unsigned ls = 0;
#pragma unroll
  for (int i = 0; i < 16; ++i) { v[i] = hist[t * 16 + i]; ls += v[i]; }
  ps[t] = ls;
  __syncthreads();
  unsigned total = 0;
  for (int i = 0; i < 256; ++i) total += ps[i];
  unsigned half = (total + 1) / 2;
  unsigned before = 0;
  for (int i = 0; i < t; ++i) before += ps[i];
  if (before < half && before + ls >= half) {      // exactly one thread
    unsigned cum = before; int mb = t * 16 + 15;
#pragma unroll
    for (int i = 0; i < 16; ++i) { cum += v[i]; if (cum >= half) { mb = t * 16 + i; break; } }
    float median = ((float)mb + 0.5f) * 0.125f;
    c1[0] = logf((float)(NROWS + 1)) / median;     // 1/(2*sigma)
  }
}

// ---- K4: fused kernel. 128x128 tile, bf16 MFMA 16x16x32 with SWAPPED operands
//      (A = y-tile, B = x-tile) so each lane's 4 acc regs are 4 consecutive
//      output COLUMNS -> float4 stores (1KB per wave store instr). ----
__global__ __launch_bounds__(256) void kxy_k(
    const float* __restrict__ x, const float* __restrict__ y,
    const float* __restrict__ sx, const float* __restrict__ sy,
    const float* __restrict__ c1p, float* __restrict__ out) {
  // XOR-swizzled LDS tiles [128 rows][64 bf16] (128B rows): byte ^= (row&7)<<4
  __shared__ unsigned short lA[128 * 64];          // x tile
  __shared__ unsigned short lB[128 * 64];          // y tile

  // XCD-bijective block swizzle (nwg=4096, 4096%8==0)
  int wg  = blockIdx.x;
  int swz = (wg & 7) * 512 + (wg >> 3);
  int bm  = swz >> 6, bn = swz & 63;               // bm: x tile, bn: y tile

  const int tid = threadIdx.x;
  const float* xT = x + (size_t)bm * 128 * DDIM;
  const float* yT = y + (size_t)bn * 128 * DDIM;

  // stage + convert: 128x64 f32 -> bf16, both tiles
#pragma unroll
  for (int it = 0; it < 8; ++it) {
    int f   = tid + it * 256;                      // float4 index, 0..2047
    int row = f >> 4;
    int c4  = (f & 15) << 2;
    f4 a = *(const f4*)(xT + row * DDIM + c4);
    f4 b = *(const f4*)(yT + row * DDIM + c4);
    us4 pa, pb;
    pa.x = f2bf(a.x); pa.y = f2bf(a.y); pa.z = f2bf(a.z); pa.w = f2bf(a.w);
    pb.x = f2bf(b.x); pb.y = f2bf(b.y); pb.z = f2bf(b.z); pb.w = f2bf(b.w);
    int off = row * 128 + (c4 << 1);
    int sz  = off ^ ((row & 7) << 4);
    *(us4*)((char*)lA + sz) = pa;
    *(us4*)((char*)lB + sz) = pb;
  }
  __syncthreads();

  const int lane = tid & 63;
  const int wv   = tid >> 6;
  const int wr   = wv >> 1, wc = wv & 1;           // wr: y half (M), wc: x half (N)
  const int l15  = lane & 15;
  const int kg   = lane >> 4;

  f4 acc[4][4];                                    // [m: y 16-blk][n: x 16-blk]
  f4 zero = {0.f, 0.f, 0.f, 0.f};
#pragma unroll
  for (int m = 0; m < 4; ++m)
#pragma unroll
    for (int n = 0; n < 4; ++n) acc[m][n] = zero;

#pragma unroll
  for (int ks = 0; ks < 2; ++ks) {                 // K = 64 = 2 x 32
    bf16x8 af[4], bf[4];
    int kB = (ks * 32 + kg * 8) << 1;              // byte offset of k-octet
#pragma unroll
    for (int m = 0; m < 4; ++m) {                  // A = y rows
      int r = wr * 64 + m * 16 + l15;
      int off = r * 128 + kB;
      af[m] = *(const bf16x8*)((const char*)lB + (off ^ ((r & 7) << 4)));
    }
#pragma unroll
    for (int n = 0; n < 4; ++n) {                  // B = x rows
      int r = wc * 64 + n * 16 + l15;
      int off = r * 128 + kB;
      bf[n] = *(const bf16x8*)((const char*)lA + (off ^ ((r & 7) << 4)));
    }
#pragma unroll
    for (int m = 0; m < 4; ++m)
#pragma unroll
      for (int n = 0; n < 4; ++n)
        acc[m][n] = __builtin_amdgcn_mfma_f32_16x16x32_bf16(af[m], bf[n], acc[m][n], 0, 0, 0);
  }

  // epilogue: D[m][n] lane layout: out-row (x) = wc*64+n*16+l15 (fixed/lane),
  // out-cols (y) = wr*64+m*16+kg*4+rg -> one f4 store per (m,n)
  float c1 = c1p[0];                               // 1/(2*sigma)
  int ib = bm * 128 + wc * 64;                     // x base (out row)
  int jb = bn * 128 + wr * 64;                     // y base (out col)
  float sxv[4];
#pragma unroll
  for (int n = 0; n < 4; ++n) sxv[n] = sx[ib + n * 16 + l15];
#pragma unroll
  for (int m = 0; m < 4; ++m) {
    int jcol = jb + m * 16 + kg * 4;
    f4 syv = *(const f4*)&sy[jcol];
#pragma unroll
    for (int n = 0; n < 4; ++n) {
      int irow = ib + n * 16 + l15;
      f4 inner = acc[m][n];
      f4 r;
#pragma unroll
      for (int rg = 0; rg < 4; ++rg) {
        float pd = sxv[n] + syv[rg] - 2.f * inner[rg];
        r[rg] = __expf(-pd * c1) + RMIX * inner[rg] * inner[rg];
      }
      *(f4*)&out[(size_t)irow * NROWS + jcol] = r;
    }
  }
}

extern "C" void kernel_launch(void* const* d_in, const int* in_sizes, int n_in,
                              void* d_out, int out_size, void* d_ws, size_t ws_size,
                              hipStream_t stream) {
  const float* x = (const float*)d_in[0];
  const float* y = (const float*)d_in[1];
  float* out = (float*)d_out;

  // workspace: sx[8192] f32 | sy[8192] f32 | hist[4096] u32 | c1[1] f32
  float*    sx   = (float*)d_ws;
  float*    sy   = sx + NROWS;
  unsigned* hist = (unsigned*)(sy + NROWS);
  float*    c1   = (float*)(hist + HBINS);

  hipLaunchKernelGGL(norms_k, dim3(65), dim3(256), 0, stream, x, y, sx, sy, hist);
  hipLaunchKernelGGL(hist_k, dim3(64), dim3(256), 0, stream, x, y, sx, sy, hist);
  hipLaunchKernelGGL(scan_k, dim3(1), dim3(256), 0, stream, hist, c1);
  hipLaunchKernelGGL(kxy_k, dim3(4096), dim3(256), 0, stream, x, y, sx, sy, c1, out);
}